// Round 1
// baseline (348.564 us; speedup 1.0000x reference)
//
#include <hip/hip_runtime.h>
#include <math.h>

// ---------------------------------------------------------------------------
// TGCN: z/r/h GCN gates + GRU + readout.
// Trick: segment_sum(w * (x@W)[src]) == segment_sum(w * x[src]) @ W
// -> aggregate raw features ONCE (AX), fold W_g into Wl_g top half on device.
// ---------------------------------------------------------------------------

__global__ __launch_bounds__(256) void zero_kernel(float* __restrict__ p, int n4) {
    int i = blockIdx.x * blockDim.x + threadIdx.x;
    int stride = gridDim.x * blockDim.x;
    float4 z = make_float4(0.f, 0.f, 0.f, 0.f);
    for (; i < n4; i += stride) ((float4*)p)[i] = z;
}

// Wf[g] = W_g @ Wl_g[0:64]   (64x64),  bf[g] = b_g @ Wl_g[0:64] + bl_g
__global__ __launch_bounds__(256) void fuse_weights_kernel(
    const float* __restrict__ Wz, const float* __restrict__ Wr, const float* __restrict__ Wh,
    const float* __restrict__ bz, const float* __restrict__ br, const float* __restrict__ bh,
    const float* __restrict__ Wlz, const float* __restrict__ Wlr, const float* __restrict__ Wlh,
    const float* __restrict__ blz, const float* __restrict__ blr, const float* __restrict__ blh,
    float* __restrict__ Wf, float* __restrict__ bf)
{
    int g = blockIdx.x;
    const float* Win = (g == 0) ? Wz : (g == 1) ? Wr : Wh;
    const float* Wl  = (g == 0) ? Wlz : (g == 1) ? Wlr : Wlh;
    const float* b   = (g == 0) ? bz : (g == 1) ? br : bh;
    const float* bl  = (g == 0) ? blz : (g == 1) ? blr : blh;

    __shared__ float wl_s[64][64];
    int tid = threadIdx.x;
    for (int i = tid; i < 64 * 64; i += 256) wl_s[i >> 6][i & 63] = Wl[i];
    __syncthreads();

    int k = tid >> 2;
    int j0 = (tid & 3) << 4;
    float acc[16];
#pragma unroll
    for (int jj = 0; jj < 16; jj++) acc[jj] = 0.f;
    for (int t = 0; t < 64; t++) {
        float a = Win[k * 64 + t];
#pragma unroll
        for (int jj = 0; jj < 16; jj++) acc[jj] = fmaf(a, wl_s[t][j0 + jj], acc[jj]);
    }
#pragma unroll
    for (int jj = 0; jj < 16; jj++) Wf[g * 4096 + k * 64 + j0 + jj] = acc[jj];

    if (tid < 64) {
        float a2 = bl[tid];
        for (int t = 0; t < 64; t++) a2 = fmaf(b[t], wl_s[t][tid], a2);
        bf[g * 64 + tid] = a2;
    }
}

// AX[dst] += w * x[src]   (one wave per edge, lane = feature)
__global__ __launch_bounds__(256) void scatter_kernel(
    const float* __restrict__ x, const float* __restrict__ ew,
    const int* __restrict__ ei, float* __restrict__ AX, int E)
{
    int wid  = (blockIdx.x * 256 + threadIdx.x) >> 6;
    int lane = threadIdx.x & 63;
    int nw   = (gridDim.x * 256) >> 6;
    for (int e = wid; e < E; e += nw) {
        int src = ei[e];
        int dst = ei[E + e];
        float w = ew[e];
        float v = x[(size_t)src * 64 + lane];
        atomicAdd(&AX[(size_t)dst * 64 + lane], w * v);
    }
}

__device__ __forceinline__ float sigmoid_(float x) { return 1.0f / (1.0f + __expf(-x)); }
__device__ __forceinline__ float tanh_(float x)    { return 1.0f - 2.0f / (__expf(2.0f * x) + 1.0f); }

// Fused GRU gates + output: per 64-node tile.
__global__ __launch_bounds__(256, 2) void gates_kernel(
    const float* __restrict__ AX, const float* __restrict__ hid,
    const float* __restrict__ Wf, const float* __restrict__ bf,
    const float* __restrict__ Wlz, const float* __restrict__ Wlr, const float* __restrict__ Wlh,
    const float* __restrict__ Wout, const float* __restrict__ bout,
    float* __restrict__ outY, float* __restrict__ outH, int nNodes)
{
    __shared__ float axs[64][68];
    __shared__ float hs[64][68];
    __shared__ float rs[64][68];
    __shared__ float wbuf[64 * 64];
    __shared__ float bsh[64];

    const int tid = threadIdx.x;
    const int row = tid >> 2;
    const int c0  = (tid & 3) << 4;
    const int n   = blockIdx.x * 64 + row;
    const bool valid = n < nNodes;

    // stage AX / hidden tiles (zero-fill invalid rows)
    {
        const float4 z4 = make_float4(0.f, 0.f, 0.f, 0.f);
#pragma unroll
        for (int q = 0; q < 4; q++) {
            float4 va = valid ? *(const float4*)(AX  + (size_t)n * 64 + c0 + q * 4) : z4;
            float4 vh = valid ? *(const float4*)(hid + (size_t)n * 64 + c0 + q * 4) : z4;
            *(float4*)(&axs[row][c0 + q * 4]) = va;
            *(float4*)(&hs [row][c0 + q * 4]) = vh;
        }
    }

    auto loadW = [&](const float* __restrict__ W) {
#pragma unroll
        for (int i = 0; i < 4; i++)
            ((float4*)wbuf)[tid + i * 256] = ((const float4*)W)[tid + i * 256];
    };

    auto MM = [&](float* acc, const float (*S)[68]) {
        const float* srow = S[row];
#pragma unroll 4
        for (int k = 0; k < 64; k += 4) {
            float4 a4 = *(const float4*)(srow + k);
#pragma unroll
            for (int kk = 0; kk < 4; kk++) {
                float a = (kk == 0) ? a4.x : (kk == 1) ? a4.y : (kk == 2) ? a4.z : a4.w;
                const float4* wr = (const float4*)(wbuf + ((k + kk) << 6) + c0);
                float4 w0 = wr[0], w1 = wr[1], w2 = wr[2], w3 = wr[3];
                acc[0]  = fmaf(a, w0.x, acc[0]);   acc[1]  = fmaf(a, w0.y, acc[1]);
                acc[2]  = fmaf(a, w0.z, acc[2]);   acc[3]  = fmaf(a, w0.w, acc[3]);
                acc[4]  = fmaf(a, w1.x, acc[4]);   acc[5]  = fmaf(a, w1.y, acc[5]);
                acc[6]  = fmaf(a, w1.z, acc[6]);   acc[7]  = fmaf(a, w1.w, acc[7]);
                acc[8]  = fmaf(a, w2.x, acc[8]);   acc[9]  = fmaf(a, w2.y, acc[9]);
                acc[10] = fmaf(a, w2.z, acc[10]);  acc[11] = fmaf(a, w2.w, acc[11]);
                acc[12] = fmaf(a, w3.x, acc[12]);  acc[13] = fmaf(a, w3.y, acc[13]);
                acc[14] = fmaf(a, w3.z, acc[14]);  acc[15] = fmaf(a, w3.w, acc[15]);
            }
        }
    };

    float zreg[16], tmp[16];

    // ---- gate z: sigmoid(AX@Wz' + hid@Wlz_bot + bz')
    if (tid < 64) bsh[tid] = bf[tid];
    loadW(Wf);                       // Wz' (fused)
    __syncthreads();
#pragma unroll
    for (int jj = 0; jj < 16; jj++) zreg[jj] = bsh[c0 + jj];
    MM(zreg, axs);
    __syncthreads();
    loadW(Wlz + 4096);               // bottom half of Wl_z
    __syncthreads();
    MM(zreg, hs);
#pragma unroll
    for (int jj = 0; jj < 16; jj++) zreg[jj] = sigmoid_(zreg[jj]);
    __syncthreads();

    // ---- gate r: sigmoid(AX@Wr' + hid@Wlr_bot + br');  rs <- r * hid
    if (tid < 64) bsh[tid] = bf[64 + tid];
    loadW(Wf + 4096);
    __syncthreads();
#pragma unroll
    for (int jj = 0; jj < 16; jj++) tmp[jj] = bsh[c0 + jj];
    MM(tmp, axs);
    __syncthreads();
    loadW(Wlr + 4096);
    __syncthreads();
    MM(tmp, hs);
#pragma unroll
    for (int jj = 0; jj < 16; jj++)
        rs[row][c0 + jj] = sigmoid_(tmp[jj]) * hs[row][c0 + jj];
    __syncthreads();

    // ---- h_tilde: tanh(AX@Wh' + (r*hid)@Wlh_bot + bh')
    if (tid < 64) bsh[tid] = bf[128 + tid];
    loadW(Wf + 8192);
    __syncthreads();
#pragma unroll
    for (int jj = 0; jj < 16; jj++) tmp[jj] = bsh[c0 + jj];
    MM(tmp, axs);
    __syncthreads();
    loadW(Wlh + 4096);
    __syncthreads();
    MM(tmp, rs);

    // ---- h = z*hid + (1-z)*h_tilde ; write h ; rs <- relu(h)
    float hv[16];
#pragma unroll
    for (int jj = 0; jj < 16; jj++) {
        float ht = tanh_(tmp[jj]);
        hv[jj] = zreg[jj] * hs[row][c0 + jj] + (1.0f - zreg[jj]) * ht;
    }
    if (valid) {
#pragma unroll
        for (int q = 0; q < 4; q++) {
            float4 v = make_float4(hv[q * 4], hv[q * 4 + 1], hv[q * 4 + 2], hv[q * 4 + 3]);
            *(float4*)(outH + (size_t)n * 64 + c0 + q * 4) = v;
        }
    }
    __syncthreads();                 // everyone done reading rs in MM above
#pragma unroll
    for (int jj = 0; jj < 16; jj++) rs[row][c0 + jj] = fmaxf(hv[jj], 0.f);
    if (tid < 64) bsh[tid] = bout[tid];
    loadW(Wout);
    __syncthreads();

    // ---- y = relu(h) @ W_out + b_out
#pragma unroll
    for (int jj = 0; jj < 16; jj++) tmp[jj] = bsh[c0 + jj];
    MM(tmp, rs);
    if (valid) {
#pragma unroll
        for (int q = 0; q < 4; q++) {
            float4 v = make_float4(tmp[q * 4], tmp[q * 4 + 1], tmp[q * 4 + 2], tmp[q * 4 + 3]);
            *(float4*)(outY + (size_t)n * 64 + c0 + q * 4) = v;
        }
    }
}

extern "C" void kernel_launch(void* const* d_in, const int* in_sizes, int n_in,
                              void* d_out, int out_size, void* d_ws, size_t ws_size,
                              hipStream_t stream)
{
    const float* node_feat = (const float*)d_in[0];
    const float* edge_w    = (const float*)d_in[1];
    const float* hidden    = (const float*)d_in[2];
    const float* W_z  = (const float*)d_in[3];
    const float* b_z  = (const float*)d_in[4];
    const float* W_r  = (const float*)d_in[5];
    const float* b_r  = (const float*)d_in[6];
    const float* W_h  = (const float*)d_in[7];
    const float* b_h  = (const float*)d_in[8];
    const float* Wl_z = (const float*)d_in[9];
    const float* bl_z = (const float*)d_in[10];
    const float* Wl_r = (const float*)d_in[11];
    const float* bl_r = (const float*)d_in[12];
    const float* Wl_h = (const float*)d_in[13];
    const float* bl_h = (const float*)d_in[14];
    const float* W_out = (const float*)d_in[15];
    const float* b_out = (const float*)d_in[16];
    const int*   edge_index = (const int*)d_in[17];

    const int N = in_sizes[0] / 64;
    const int E = in_sizes[1];

    float* AX = (float*)d_ws;                 // [N,64]
    float* Wf = AX + (size_t)N * 64;          // 3 x 64x64 fused weights
    float* bf = Wf + 3 * 4096;                // 3 x 64 fused biases

    float* outY = (float*)d_out;              // [N,64]
    float* outH = outY + (size_t)N * 64;      // [N,64]

    zero_kernel<<<2048, 256, 0, stream>>>(AX, N * 16);
    fuse_weights_kernel<<<3, 256, 0, stream>>>(W_z, W_r, W_h, b_z, b_r, b_h,
                                               Wl_z, Wl_r, Wl_h, bl_z, bl_r, bl_h, Wf, bf);
    scatter_kernel<<<2048, 256, 0, stream>>>(node_feat, edge_w, edge_index, AX, E);

    int nblk = (N + 63) / 64;
    gates_kernel<<<nblk, 256, 0, stream>>>(AX, hidden, Wf, bf,
                                           Wl_z, Wl_r, Wl_h, W_out, b_out,
                                           outY, outH, N);
}

// Round 2
// 246.971 us; speedup vs baseline: 1.4114x; 1.4114x over previous
//
#include <hip/hip_runtime.h>
#include <hip/hip_bf16.h>
#include <math.h>

// ---------------------------------------------------------------------------
// TGCN: z/r/h GCN gates + GRU + readout.
// R1: segment_sum(w * (x@W)[src]) == segment_sum(w * x[src]) @ W
//     -> aggregate raw features ONCE (AX), fold W_g into Wl_g top half.
// R2: gate GEMMs on MFMA (bf16 in, f32 acc). Weights pre-transposed/bf16 in
//     d_ws; each wave holds all 7 B-operand fragment sets in registers.
// ---------------------------------------------------------------------------

typedef __attribute__((ext_vector_type(8))) short bf16x8;   // 8 bf16 = 4 VGPR
typedef __attribute__((ext_vector_type(4))) float f32x4;    // MFMA C/D

static __device__ __forceinline__ short f2bf(float x) {
    union { float f; unsigned u; } v; v.f = x;
    unsigned r = v.u + 0x7fffu + ((v.u >> 16) & 1u);        // RNE
    return (short)(r >> 16);
}
__device__ __forceinline__ float sigmoid_(float x) { return 1.0f / (1.0f + __expf(-x)); }
__device__ __forceinline__ float tanh_(float x)    { return 1.0f - 2.0f / (__expf(2.0f * x) + 1.0f); }

__global__ __launch_bounds__(256) void zero_kernel(float* __restrict__ p, int n4) {
    int i = blockIdx.x * blockDim.x + threadIdx.x;
    int stride = gridDim.x * blockDim.x;
    float4 z = make_float4(0.f, 0.f, 0.f, 0.f);
    for (; i < n4; i += stride) ((float4*)p)[i] = z;
}

// Produces, in d_ws:
//   WT[m][64][64] bf16, n-major (transposed), m = 0..6:
//     0..2 : W_g @ Wl_g_top   (fused GCN+gate weight)
//     3..5 : Wl_g_bottom
//     6    : W_out
//   bfv[4][64] f32: fused biases b_g@Wl_g_top + bl_g (g=0..2), b_out (3)
__global__ __launch_bounds__(256) void fuse_weights_kernel(
    const float* __restrict__ Wz, const float* __restrict__ Wr, const float* __restrict__ Wh,
    const float* __restrict__ bz, const float* __restrict__ br, const float* __restrict__ bh,
    const float* __restrict__ Wlz, const float* __restrict__ Wlr, const float* __restrict__ Wlh,
    const float* __restrict__ blz, const float* __restrict__ blr, const float* __restrict__ blh,
    const float* __restrict__ Wout, const float* __restrict__ bout_,
    short* __restrict__ WT, float* __restrict__ bfv)
{
    int g = blockIdx.x;
    int tid = threadIdx.x;
    if (g == 3) {
        for (int i = tid; i < 4096; i += 256) {
            int k = i >> 6, n = i & 63;
            WT[6 * 4096 + n * 64 + k] = f2bf(Wout[k * 64 + n]);
        }
        if (tid < 64) bfv[192 + tid] = bout_[tid];
        return;
    }
    const float* Win = (g == 0) ? Wz : (g == 1) ? Wr : Wh;
    const float* Wl  = (g == 0) ? Wlz : (g == 1) ? Wlr : Wlh;
    const float* b   = (g == 0) ? bz : (g == 1) ? br : bh;
    const float* bl  = (g == 0) ? blz : (g == 1) ? blr : blh;

    __shared__ float wl_s[64][65];
    for (int i = tid; i < 4096; i += 256) wl_s[i >> 6][i & 63] = Wl[i];
    __syncthreads();

    int k = tid >> 2;
    int j0 = (tid & 3) << 4;
    float acc[16];
#pragma unroll
    for (int jj = 0; jj < 16; jj++) acc[jj] = 0.f;
    for (int t = 0; t < 64; t++) {
        float a = Win[k * 64 + t];
#pragma unroll
        for (int jj = 0; jj < 16; jj++) acc[jj] = fmaf(a, wl_s[t][j0 + jj], acc[jj]);
    }
#pragma unroll
    for (int jj = 0; jj < 16; jj++) WT[g * 4096 + (j0 + jj) * 64 + k] = f2bf(acc[jj]);

    for (int i = tid; i < 4096; i += 256) {        // bottom half of Wl, transposed
        int kk = i >> 6, n = i & 63;
        WT[(3 + g) * 4096 + n * 64 + kk] = f2bf(Wl[(64 + kk) * 64 + n]);
    }
    if (tid < 64) {
        float a2 = bl[tid];
        for (int t = 0; t < 64; t++) a2 = fmaf(b[t], wl_s[t][tid], a2);
        bfv[g * 64 + tid] = a2;
    }
}

// AX[dst] += w * x[src]   (one wave per edge, lane = feature)
__global__ __launch_bounds__(256) void scatter_kernel(
    const float* __restrict__ x, const float* __restrict__ ew,
    const int* __restrict__ ei, float* __restrict__ AX, int E)
{
    int wid  = (blockIdx.x * 256 + threadIdx.x) >> 6;
    int lane = threadIdx.x & 63;
    int nw   = (gridDim.x * 256) >> 6;
    for (int e = wid; e < E; e += nw) {
        int src = ei[e];
        int dst = ei[E + e];
        float w = ew[e];
        float v = x[(size_t)src * 64 + lane];
        atomicAdd(&AX[(size_t)dst * 64 + lane], w * v);
    }
}

// Fused GRU gates + readout via MFMA. 64-node tile, 4 waves.
// Wave w owns output cols [w*16, w*16+16); all B-fragments live in VGPRs.
__global__ __launch_bounds__(256, 3) void gates_kernel(
    const float* __restrict__ AX, const float* __restrict__ hid,
    const short* __restrict__ WT, const float* __restrict__ bfv,
    float* __restrict__ outY, float* __restrict__ outH, int nNodes)
{
    __shared__ short axs[64][72];   // AX tile bf16 (later reused for relu(h))
    __shared__ short hs [64][72];   // hid tile bf16 (MFMA A-operand)
    __shared__ short rsb[64][72];   // r * hid, bf16
    __shared__ float hf [64][68];   // hid tile f32 (exact elementwise)

    const int tid  = threadIdx.x;
    const int w    = tid >> 6;
    const int lane = tid & 63;
    const int lr   = lane & 15;     // row-in-tile (A) / col-in-tile (B,C)
    const int lg   = lane >> 4;     // k-group
    const int col  = w * 16 + lr;   // output column owned by this lane
    const int n0   = blockIdx.x * 64;

    // ---- stage AX / hid tiles
    {
        int row = tid >> 2;
        int c0  = (tid & 3) << 4;
        int n   = n0 + row;
        bool valid = n < nNodes;
        const float4 z4 = make_float4(0.f, 0.f, 0.f, 0.f);
#pragma unroll
        for (int q = 0; q < 4; q++) {
            float4 va = valid ? *(const float4*)(AX  + (size_t)n * 64 + c0 + q * 4) : z4;
            float4 vh = valid ? *(const float4*)(hid + (size_t)n * 64 + c0 + q * 4) : z4;
            int c = c0 + q * 4;
            axs[row][c + 0] = f2bf(va.x); axs[row][c + 1] = f2bf(va.y);
            axs[row][c + 2] = f2bf(va.z); axs[row][c + 3] = f2bf(va.w);
            hs [row][c + 0] = f2bf(vh.x); hs [row][c + 1] = f2bf(vh.y);
            hs [row][c + 2] = f2bf(vh.z); hs [row][c + 3] = f2bf(vh.w);
            hf [row][c + 0] = vh.x; hf [row][c + 1] = vh.y;
            hf [row][c + 2] = vh.z; hf [row][c + 3] = vh.w;
        }
    }

    // ---- B-operand fragments for all 7 matrices, 2 k-steps each (56 VGPR)
    // WT[m] is [n][k] bf16; lane needs n=col, k = kb*32 + lg*8 + 0..7 (16B).
    bf16x8 wf[7][2];
#pragma unroll
    for (int m = 0; m < 7; m++)
#pragma unroll
        for (int kb = 0; kb < 2; kb++)
            wf[m][kb] = *(const bf16x8*)(WT + m * 4096 + col * 64 + kb * 32 + lg * 8);
    const float bz_ = bfv[col], br_ = bfv[64 + col], bh_ = bfv[128 + col], bo_ = bfv[192 + col];

    __syncthreads();

    const f32x4 zero4 = {0.f, 0.f, 0.f, 0.f};
    f32x4 accz[4], accr[4], acch[4];
#pragma unroll
    for (int rt = 0; rt < 4; rt++) { accz[rt] = zero4; accr[rt] = zero4; acch[rt] = zero4; }

    // ---- phase A: AX-part of z,r,h and hid-part of z,r
#pragma unroll
    for (int rt = 0; rt < 4; rt++) {
        int arow = rt * 16 + lr;
#pragma unroll
        for (int kb = 0; kb < 2; kb++) {
            bf16x8 aa = *(const bf16x8*)(&axs[arow][kb * 32 + lg * 8]);
            bf16x8 ah = *(const bf16x8*)(&hs [arow][kb * 32 + lg * 8]);
            accz[rt] = __builtin_amdgcn_mfma_f32_16x16x32_bf16(aa, wf[0][kb], accz[rt], 0, 0, 0);
            accr[rt] = __builtin_amdgcn_mfma_f32_16x16x32_bf16(aa, wf[1][kb], accr[rt], 0, 0, 0);
            acch[rt] = __builtin_amdgcn_mfma_f32_16x16x32_bf16(aa, wf[2][kb], acch[rt], 0, 0, 0);
            accz[rt] = __builtin_amdgcn_mfma_f32_16x16x32_bf16(ah, wf[3][kb], accz[rt], 0, 0, 0);
            accr[rt] = __builtin_amdgcn_mfma_f32_16x16x32_bf16(ah, wf[4][kb], accr[rt], 0, 0, 0);
        }
    }

    // ---- z, r; rsb <- bf16(r * hid)   (C layout: row = rt*16 + lg*4 + i, col)
    float zf[16];
#pragma unroll
    for (int rt = 0; rt < 4; rt++) {
#pragma unroll
        for (int i = 0; i < 4; i++) {
            int row = rt * 16 + lg * 4 + i;
            float z = sigmoid_(accz[rt][i] + bz_);
            float r = sigmoid_(accr[rt][i] + br_);
            zf[rt * 4 + i] = z;
            rsb[row][col] = f2bf(r * hf[row][col]);
        }
    }
    __syncthreads();

    // ---- phase B: h_tilde += (r*hid) @ Wlh_bot ; h ; relu(h) -> axs
#pragma unroll
    for (int rt = 0; rt < 4; rt++) {
        int arow = rt * 16 + lr;
#pragma unroll
        for (int kb = 0; kb < 2; kb++) {
            bf16x8 ar = *(const bf16x8*)(&rsb[arow][kb * 32 + lg * 8]);
            acch[rt] = __builtin_amdgcn_mfma_f32_16x16x32_bf16(ar, wf[5][kb], acch[rt], 0, 0, 0);
        }
    }
#pragma unroll
    for (int rt = 0; rt < 4; rt++) {
#pragma unroll
        for (int i = 0; i < 4; i++) {
            int row = rt * 16 + lg * 4 + i;
            float ht = tanh_(acch[rt][i] + bh_);
            float z  = zf[rt * 4 + i];
            float hv = z * hf[row][col] + (1.f - z) * ht;
            int n = n0 + row;
            if (n < nNodes) outH[(size_t)n * 64 + col] = hv;
            axs[row][col] = f2bf(fmaxf(hv, 0.f));
        }
    }
    __syncthreads();

    // ---- phase C: y = relu(h) @ W_out + b_out
    f32x4 accy[4];
#pragma unroll
    for (int rt = 0; rt < 4; rt++) accy[rt] = zero4;
#pragma unroll
    for (int rt = 0; rt < 4; rt++) {
        int arow = rt * 16 + lr;
#pragma unroll
        for (int kb = 0; kb < 2; kb++) {
            bf16x8 aa = *(const bf16x8*)(&axs[arow][kb * 32 + lg * 8]);
            accy[rt] = __builtin_amdgcn_mfma_f32_16x16x32_bf16(aa, wf[6][kb], accy[rt], 0, 0, 0);
        }
    }
#pragma unroll
    for (int rt = 0; rt < 4; rt++) {
#pragma unroll
        for (int i = 0; i < 4; i++) {
            int row = rt * 16 + lg * 4 + i;
            int n = n0 + row;
            if (n < nNodes) outY[(size_t)n * 64 + col] = accy[rt][i] + bo_;
        }
    }
}

extern "C" void kernel_launch(void* const* d_in, const int* in_sizes, int n_in,
                              void* d_out, int out_size, void* d_ws, size_t ws_size,
                              hipStream_t stream)
{
    const float* node_feat = (const float*)d_in[0];
    const float* edge_w    = (const float*)d_in[1];
    const float* hidden    = (const float*)d_in[2];
    const float* W_z  = (const float*)d_in[3];
    const float* b_z  = (const float*)d_in[4];
    const float* W_r  = (const float*)d_in[5];
    const float* b_r  = (const float*)d_in[6];
    const float* W_h  = (const float*)d_in[7];
    const float* b_h  = (const float*)d_in[8];
    const float* Wl_z = (const float*)d_in[9];
    const float* bl_z = (const float*)d_in[10];
    const float* Wl_r = (const float*)d_in[11];
    const float* bl_r = (const float*)d_in[12];
    const float* Wl_h = (const float*)d_in[13];
    const float* bl_h = (const float*)d_in[14];
    const float* W_out = (const float*)d_in[15];
    const float* b_out = (const float*)d_in[16];
    const int*   edge_index = (const int*)d_in[17];

    const int N = in_sizes[0] / 64;
    const int E = in_sizes[1];

    float* AX  = (float*)d_ws;                  // [N,64] f32
    short* WT  = (short*)(AX + (size_t)N * 64); // 7 x 64x64 bf16 (transposed)
    float* bfv = (float*)(WT + 7 * 4096);       // 4 x 64 f32 biases

    float* outY = (float*)d_out;                // [N,64]
    float* outH = outY + (size_t)N * 64;        // [N,64]

    zero_kernel<<<2048, 256, 0, stream>>>(AX, N * 16);
    fuse_weights_kernel<<<4, 256, 0, stream>>>(W_z, W_r, W_h, b_z, b_r, b_h,
                                               Wl_z, Wl_r, Wl_h, bl_z, bl_r, bl_h,
                                               W_out, b_out, WT, bfv);
    scatter_kernel<<<2048, 256, 0, stream>>>(node_feat, edge_w, edge_index, AX, E);

    int nblk = (N + 63) / 64;
    gates_kernel<<<nblk, 256, 0, stream>>>(AX, hidden, WT, bfv, outY, outH, N);
}

// Round 3
// 151.717 us; speedup vs baseline: 2.2975x; 1.6278x over previous
//
#include <hip/hip_runtime.h>
#include <hip/hip_bf16.h>
#include <math.h>

// ---------------------------------------------------------------------------
// TGCN: z/r/h GCN gates + GRU + readout.
// R1: segment_sum(w * (x@W)[src]) == segment_sum(w * x[src]) @ W
//     -> aggregate raw features ONCE (AX), fold W_g into Wl_g top half.
// R2: gate GEMMs on MFMA (bf16 in, f32 acc); weights pre-fused in d_ws.
// R3: scatter was atomic-dword-throughput bound (125/cycle ~= 128 ceiling).
//     -> bf16 AX accumulator with global_atomic_pk_add_bf16 (2 feat/atomic),
//        x pre-converted to bf16 (half gather bytes), AX read as bf16 in gates.
// ---------------------------------------------------------------------------

typedef __attribute__((ext_vector_type(8))) short bf16x8;   // 8 bf16 = 4 VGPR
typedef __attribute__((ext_vector_type(4))) float f32x4;    // MFMA C/D

static __device__ __forceinline__ short f2bf(float x) {
    union { float f; unsigned u; } v; v.f = x;
    unsigned r = v.u + 0x7fffu + ((v.u >> 16) & 1u);        // RNE
    return (short)(r >> 16);
}
__device__ __forceinline__ float sigmoid_(float x) { return 1.0f / (1.0f + __expf(-x)); }
__device__ __forceinline__ float tanh_(float x)    { return 1.0f - 2.0f / (__expf(2.0f * x) + 1.0f); }

// xb = bf16(x); AXb = 0   (8 elements per thread)
__global__ __launch_bounds__(256) void prep_kernel(
    const float* __restrict__ x, short* __restrict__ xb,
    short* __restrict__ AXb, int n8)
{
    int i = blockIdx.x * blockDim.x + threadIdx.x;
    int stride = gridDim.x * blockDim.x;
    for (; i < n8; i += stride) {
        float4 a = ((const float4*)x)[i * 2];
        float4 b = ((const float4*)x)[i * 2 + 1];
        bf16x8 v;
        v[0] = f2bf(a.x); v[1] = f2bf(a.y); v[2] = f2bf(a.z); v[3] = f2bf(a.w);
        v[4] = f2bf(b.x); v[5] = f2bf(b.y); v[6] = f2bf(b.z); v[7] = f2bf(b.w);
        ((bf16x8*)xb)[i] = v;
        bf16x8 z = {0, 0, 0, 0, 0, 0, 0, 0};
        ((bf16x8*)AXb)[i] = z;
    }
}

// Produces, in d_ws:
//   WT[m][64][64] bf16, n-major (transposed), m = 0..6:
//     0..2 : W_g @ Wl_g_top   (fused GCN+gate weight)
//     3..5 : Wl_g_bottom
//     6    : W_out
//   bfv[4][64] f32: fused biases b_g@Wl_g_top + bl_g (g=0..2), b_out (3)
__global__ __launch_bounds__(256) void fuse_weights_kernel(
    const float* __restrict__ Wz, const float* __restrict__ Wr, const float* __restrict__ Wh,
    const float* __restrict__ bz, const float* __restrict__ br, const float* __restrict__ bh,
    const float* __restrict__ Wlz, const float* __restrict__ Wlr, const float* __restrict__ Wlh,
    const float* __restrict__ blz, const float* __restrict__ blr, const float* __restrict__ blh,
    const float* __restrict__ Wout, const float* __restrict__ bout_,
    short* __restrict__ WT, float* __restrict__ bfv)
{
    int g = blockIdx.x;
    int tid = threadIdx.x;
    if (g == 3) {
        for (int i = tid; i < 4096; i += 256) {
            int k = i >> 6, n = i & 63;
            WT[6 * 4096 + n * 64 + k] = f2bf(Wout[k * 64 + n]);
        }
        if (tid < 64) bfv[192 + tid] = bout_[tid];
        return;
    }
    const float* Win = (g == 0) ? Wz : (g == 1) ? Wr : Wh;
    const float* Wl  = (g == 0) ? Wlz : (g == 1) ? Wlr : Wlh;
    const float* b   = (g == 0) ? bz : (g == 1) ? br : bh;
    const float* bl  = (g == 0) ? blz : (g == 1) ? blr : blh;

    __shared__ float wl_s[64][65];
    for (int i = tid; i < 4096; i += 256) wl_s[i >> 6][i & 63] = Wl[i];
    __syncthreads();

    int k = tid >> 2;
    int j0 = (tid & 3) << 4;
    float acc[16];
#pragma unroll
    for (int jj = 0; jj < 16; jj++) acc[jj] = 0.f;
    for (int t = 0; t < 64; t++) {
        float a = Win[k * 64 + t];
#pragma unroll
        for (int jj = 0; jj < 16; jj++) acc[jj] = fmaf(a, wl_s[t][j0 + jj], acc[jj]);
    }
#pragma unroll
    for (int jj = 0; jj < 16; jj++) WT[g * 4096 + (j0 + jj) * 64 + k] = f2bf(acc[jj]);

    for (int i = tid; i < 4096; i += 256) {        // bottom half of Wl, transposed
        int kk = i >> 6, n = i & 63;
        WT[(3 + g) * 4096 + n * 64 + kk] = f2bf(Wl[(64 + kk) * 64 + n]);
    }
    if (tid < 64) {
        float a2 = bl[tid];
        for (int t = 0; t < 64; t++) a2 = fmaf(b[t], wl_s[t][tid], a2);
        bfv[g * 64 + tid] = a2;
    }
}

// AXb[dst] += bf16(w * xb[src])  — half-wave per edge, lane-dword = 2 features,
// one packed bf16 atomic per dword (halves atomic op count vs f32).
__global__ __launch_bounds__(256) void scatter_kernel(
    const short* __restrict__ xb, const float* __restrict__ ew,
    const int* __restrict__ ei, short* __restrict__ AXb, int E)
{
    int hw  = (blockIdx.x * 256 + threadIdx.x) >> 5;   // half-wave id
    int lj  = threadIdx.x & 31;                        // dword (feature pair)
    int nhw = (gridDim.x * 256) >> 5;
    for (int e = hw; e < E; e += nhw) {
        int src = ei[e];
        int dst = ei[E + e];
        float w = ew[e];
        unsigned pv = *(const unsigned*)(xb + (size_t)src * 64 + lj * 2);
        float lo = __uint_as_float(pv << 16) * w;
        float hi = __uint_as_float(pv & 0xffff0000u) * w;
        unsigned pk = (unsigned)(unsigned short)f2bf(lo)
                    | ((unsigned)(unsigned short)f2bf(hi) << 16);
        short* addr = AXb + (size_t)dst * 64 + lj * 2;
        asm volatile("global_atomic_pk_add_bf16 %0, %1, off"
                     :: "v"(addr), "v"(pk) : "memory");
    }
    asm volatile("s_waitcnt vmcnt(0)" ::: "memory");   // drain before endpgm
}

// Fused GRU gates + readout via MFMA. 64-node tile, 4 waves.
// Wave w owns output cols [w*16, w*16+16); all B-fragments live in VGPRs.
__global__ __launch_bounds__(256, 3) void gates_kernel(
    const short* __restrict__ AXb, const float* __restrict__ hid,
    const short* __restrict__ WT, const float* __restrict__ bfv,
    float* __restrict__ outY, float* __restrict__ outH, int nNodes)
{
    __shared__ short axs[64][72];   // AX tile bf16 (later reused for relu(h))
    __shared__ short hs [64][72];   // hid tile bf16 (MFMA A-operand)
    __shared__ short rsb[64][72];   // r * hid, bf16
    __shared__ float hf [64][68];   // hid tile f32 (exact elementwise)

    const int tid  = threadIdx.x;
    const int w    = tid >> 6;
    const int lane = tid & 63;
    const int lr   = lane & 15;     // row-in-tile (A) / col-in-tile (B,C)
    const int lg   = lane >> 4;     // k-group
    const int col  = w * 16 + lr;   // output column owned by this lane
    const int n0   = blockIdx.x * 64;

    // ---- stage AX (bf16 direct) / hid tiles
    {
        int row = tid >> 2;
        int c0  = (tid & 3) << 4;
        int n   = n0 + row;
        bool valid = n < nNodes;
        const float4 z4 = make_float4(0.f, 0.f, 0.f, 0.f);
        const bf16x8 zb = {0, 0, 0, 0, 0, 0, 0, 0};
        bf16x8 a0 = valid ? *(const bf16x8*)(AXb + (size_t)n * 64 + c0)     : zb;
        bf16x8 a1 = valid ? *(const bf16x8*)(AXb + (size_t)n * 64 + c0 + 8) : zb;
        *(bf16x8*)(&axs[row][c0])     = a0;
        *(bf16x8*)(&axs[row][c0 + 8]) = a1;
#pragma unroll
        for (int q = 0; q < 4; q++) {
            float4 vh = valid ? *(const float4*)(hid + (size_t)n * 64 + c0 + q * 4) : z4;
            int c = c0 + q * 4;
            hs[row][c + 0] = f2bf(vh.x); hs[row][c + 1] = f2bf(vh.y);
            hs[row][c + 2] = f2bf(vh.z); hs[row][c + 3] = f2bf(vh.w);
            hf[row][c + 0] = vh.x; hf[row][c + 1] = vh.y;
            hf[row][c + 2] = vh.z; hf[row][c + 3] = vh.w;
        }
    }

    // ---- B-operand fragments for all 7 matrices, 2 k-steps each (56 VGPR)
    bf16x8 wf[7][2];
#pragma unroll
    for (int m = 0; m < 7; m++)
#pragma unroll
        for (int kb = 0; kb < 2; kb++)
            wf[m][kb] = *(const bf16x8*)(WT + m * 4096 + col * 64 + kb * 32 + lg * 8);
    const float bz_ = bfv[col], br_ = bfv[64 + col], bh_ = bfv[128 + col], bo_ = bfv[192 + col];

    __syncthreads();

    const f32x4 zero4 = {0.f, 0.f, 0.f, 0.f};
    f32x4 accz[4], accr[4], acch[4];
#pragma unroll
    for (int rt = 0; rt < 4; rt++) { accz[rt] = zero4; accr[rt] = zero4; acch[rt] = zero4; }

    // ---- phase A: AX-part of z,r,h and hid-part of z,r
#pragma unroll
    for (int rt = 0; rt < 4; rt++) {
        int arow = rt * 16 + lr;
#pragma unroll
        for (int kb = 0; kb < 2; kb++) {
            bf16x8 aa = *(const bf16x8*)(&axs[arow][kb * 32 + lg * 8]);
            bf16x8 ah = *(const bf16x8*)(&hs [arow][kb * 32 + lg * 8]);
            accz[rt] = __builtin_amdgcn_mfma_f32_16x16x32_bf16(aa, wf[0][kb], accz[rt], 0, 0, 0);
            accr[rt] = __builtin_amdgcn_mfma_f32_16x16x32_bf16(aa, wf[1][kb], accr[rt], 0, 0, 0);
            acch[rt] = __builtin_amdgcn_mfma_f32_16x16x32_bf16(aa, wf[2][kb], acch[rt], 0, 0, 0);
            accz[rt] = __builtin_amdgcn_mfma_f32_16x16x32_bf16(ah, wf[3][kb], accz[rt], 0, 0, 0);
            accr[rt] = __builtin_amdgcn_mfma_f32_16x16x32_bf16(ah, wf[4][kb], accr[rt], 0, 0, 0);
        }
    }

    // ---- z, r; rsb <- bf16(r * hid)   (C layout: row = rt*16 + lg*4 + i, col)
    float zf[16];
#pragma unroll
    for (int rt = 0; rt < 4; rt++) {
#pragma unroll
        for (int i = 0; i < 4; i++) {
            int row = rt * 16 + lg * 4 + i;
            float z = sigmoid_(accz[rt][i] + bz_);
            float r = sigmoid_(accr[rt][i] + br_);
            zf[rt * 4 + i] = z;
            rsb[row][col] = f2bf(r * hf[row][col]);
        }
    }
    __syncthreads();

    // ---- phase B: h_tilde += (r*hid) @ Wlh_bot ; h ; relu(h) -> axs
#pragma unroll
    for (int rt = 0; rt < 4; rt++) {
        int arow = rt * 16 + lr;
#pragma unroll
        for (int kb = 0; kb < 2; kb++) {
            bf16x8 ar = *(const bf16x8*)(&rsb[arow][kb * 32 + lg * 8]);
            acch[rt] = __builtin_amdgcn_mfma_f32_16x16x32_bf16(ar, wf[5][kb], acch[rt], 0, 0, 0);
        }
    }
#pragma unroll
    for (int rt = 0; rt < 4; rt++) {
#pragma unroll
        for (int i = 0; i < 4; i++) {
            int row = rt * 16 + lg * 4 + i;
            float ht = tanh_(acch[rt][i] + bh_);
            float z  = zf[rt * 4 + i];
            float hv = z * hf[row][col] + (1.f - z) * ht;
            int n = n0 + row;
            if (n < nNodes) outH[(size_t)n * 64 + col] = hv;
            axs[row][col] = f2bf(fmaxf(hv, 0.f));
        }
    }
    __syncthreads();

    // ---- phase C: y = relu(h) @ W_out + b_out
    f32x4 accy[4];
#pragma unroll
    for (int rt = 0; rt < 4; rt++) accy[rt] = zero4;
#pragma unroll
    for (int rt = 0; rt < 4; rt++) {
        int arow = rt * 16 + lr;
#pragma unroll
        for (int kb = 0; kb < 2; kb++) {
            bf16x8 aa = *(const bf16x8*)(&axs[arow][kb * 32 + lg * 8]);
            accy[rt] = __builtin_amdgcn_mfma_f32_16x16x32_bf16(aa, wf[6][kb], accy[rt], 0, 0, 0);
        }
    }
#pragma unroll
    for (int rt = 0; rt < 4; rt++) {
#pragma unroll
        for (int i = 0; i < 4; i++) {
            int row = rt * 16 + lg * 4 + i;
            int n = n0 + row;
            if (n < nNodes) outY[(size_t)n * 64 + col] = accy[rt][i] + bo_;
        }
    }
}

extern "C" void kernel_launch(void* const* d_in, const int* in_sizes, int n_in,
                              void* d_out, int out_size, void* d_ws, size_t ws_size,
                              hipStream_t stream)
{
    const float* node_feat = (const float*)d_in[0];
    const float* edge_w    = (const float*)d_in[1];
    const float* hidden    = (const float*)d_in[2];
    const float* W_z  = (const float*)d_in[3];
    const float* b_z  = (const float*)d_in[4];
    const float* W_r  = (const float*)d_in[5];
    const float* b_r  = (const float*)d_in[6];
    const float* W_h  = (const float*)d_in[7];
    const float* b_h  = (const float*)d_in[8];
    const float* Wl_z = (const float*)d_in[9];
    const float* bl_z = (const float*)d_in[10];
    const float* Wl_r = (const float*)d_in[11];
    const float* bl_r = (const float*)d_in[12];
    const float* Wl_h = (const float*)d_in[13];
    const float* bl_h = (const float*)d_in[14];
    const float* W_out = (const float*)d_in[15];
    const float* b_out = (const float*)d_in[16];
    const int*   edge_index = (const int*)d_in[17];

    const int N = in_sizes[0] / 64;
    const int E = in_sizes[1];

    short* AXb = (short*)d_ws;                   // [N,64] bf16 accumulator
    short* xb  = AXb + (size_t)N * 64;           // [N,64] bf16 features
    short* WT  = xb + (size_t)N * 64;            // 7 x 64x64 bf16 (transposed)
    float* bfv = (float*)(WT + 7 * 4096);        // 4 x 64 f32 biases

    float* outY = (float*)d_out;                 // [N,64]
    float* outH = outY + (size_t)N * 64;         // [N,64]

    prep_kernel<<<2048, 256, 0, stream>>>(node_feat, xb, AXb, N * 8);
    fuse_weights_kernel<<<4, 256, 0, stream>>>(W_z, W_r, W_h, b_z, b_r, b_h,
                                               Wl_z, Wl_r, Wl_h, bl_z, bl_r, bl_h,
                                               W_out, b_out, WT, bfv);
    scatter_kernel<<<2048, 256, 0, stream>>>(xb, edge_w, edge_index, AXb, E);

    int nblk = (N + 63) / 64;
    gates_kernel<<<nblk, 256, 0, stream>>>(AXb, hidden, WT, bfv, outY, outH, N);
}